// Round 1
// 131.790 us; speedup vs baseline: 1.0389x; 1.0389x over previous
//
#include <hip/hip_runtime.h>
#include <hip/hip_fp16.h>
#include <math.h>
#include <string.h>

#define ATOM_VOC 128
#define APO      128
#define NHEAD    16
#define D_MODEL  512
#define NB       4
#define NL       384

typedef __attribute__((ext_vector_type(8))) _Float16 f16x8;
typedef __attribute__((ext_vector_type(4))) float    f32x4;
typedef __attribute__((ext_vector_type(4))) unsigned u32x4;

#define PACK_DWORDS (ATOM_VOC * ATOM_VOC * APO)   // 2M dwords = 8 MB
#define BFT_SHORTS  (4 * 4 * 16 * 8)              // 2048 f16 = 4 KB

static __device__ inline unsigned short f2h(float x) {
    __half h = __float2half(x);
    unsigned short u; memcpy(&u, &h, 2); return u;
}

// async 16B global->LDS (wave-uniform LDS base + lane*16; source is per-lane)
static __device__ inline void gload_lds16(const void* g, void* l) {
    __builtin_amdgcn_global_load_lds(
        (const __attribute__((address_space(1))) void*)g,
        (__attribute__((address_space(3))) void*)l, 16, 0, 0);
}

// ---------------------------------------------------------------------------
// Kernel 0: packed fp16 table. Row (128 dwords = 512 B) per (ai, v), layout:
//   [phase0: 32 w-pair dw | 32 b-pair dw][phase1: 32 w-pair dw | 32 b-pair dw]
// pair p = (k=2p, k=2p+1); phase = p>>5.
//   w' = w*ag, b' = (b-mean)*ag, ag = sqrt(log2e)/(sqrt(2)*s).
// Fattened: 2048 blocks x 256 thr; thread = (row r = t>>5, unit u = t&31),
// unit -> (ph, half, q): produces 4 dst dwords (u32x4) from 8 src floats
// (2x float4, coalesced). Numerics expression-identical to the 131 µs version.
// Block 0 additionally builds the f16 B-fragment table bft.
// ---------------------------------------------------------------------------
__global__ __launch_bounds__(256) void pack_kernel(
    const float* __restrict__ apw, const float* __restrict__ apb,
    const float* __restrict__ means, const float* __restrict__ stds,
    const float* __restrict__ lin_w,
    unsigned* __restrict__ pack, unsigned short* __restrict__ bft, int write_bft)
{
    const int t     = threadIdx.x;     // 0..255
    const int r     = t >> 5;          // row within block, 0..7
    const int u     = t & 31;          // work unit within row
    const int ph    = u >> 4;          // k-phase (k<64 / k>=64)
    const int half  = (u >> 3) & 1;    // 0 = w, 1 = b
    const int q     = u & 7;           // 4-dword group within half
    const int rowid = blockIdx.x * 8 + r;
    const int ai    = rowid >> 7;
    const int v     = rowid & 127;
    const int kb    = ph * 64 + q * 8; // first k of the 8 handled here

    const size_t srcrow = ((size_t)v * ATOM_VOC + ai) * APO;
    const float* sp = (half ? apb : apw) + srcrow + kb;
    const float4 f0  = *(const float4*)(sp);
    const float4 f1  = *(const float4*)(sp + 4);
    const float4 sd0 = *(const float4*)(stds + kb);
    const float4 sd1 = *(const float4*)(stds + kb + 4);

    float x[8]  = {f0.x, f0.y, f0.z, f0.w, f1.x, f1.y, f1.z, f1.w};
    float ss[8] = {sd0.x, sd0.y, sd0.z, sd0.w, sd1.x, sd1.y, sd1.z, sd1.w};
    if (half) {
        const float4 m0 = *(const float4*)(means + kb);
        const float4 m1 = *(const float4*)(means + kb + 4);
        const float mm[8] = {m0.x, m0.y, m0.z, m0.w, m1.x, m1.y, m1.z, m1.w};
#pragma unroll
        for (int j = 0; j < 8; ++j) x[j] = x[j] - mm[j];
    }
    unsigned dw[4];
#pragma unroll
    for (int j = 0; j < 4; ++j) {
        const float ag0 = 0.84932180028802f / (fabsf(ss[2 * j])     + 1e-5f);
        const float ag1 = 0.84932180028802f / (fabsf(ss[2 * j + 1]) + 1e-5f);
        dw[j] = ((unsigned)f2h(x[2 * j + 1] * ag1) << 16) | f2h(x[2 * j] * ag0);
    }
    const int dst = ph * 64 + half * 32 + q * 4;
    *(u32x4*)&pack[((size_t)ai * ATOM_VOC + v) * APO + dst] = *(const u32x4*)dw;

    if (write_bft && blockIdx.x == 0) {
        const int cid  = t;            // 0..255
        const int ks   = cid >> 6;
        const int quad = (cid >> 4) & 3;
        const int hh   = cid & 15;
        const int kb2  = ks * 32 + quad * 8;
        unsigned short tmp[8];
#pragma unroll
        for (int uu = 0; uu < 8; ++uu) {
            const int kk = kb2 + uu;
            float z = 0.3989422804014327f / (fabsf(stds[kk]) + 1e-5f);
            tmp[uu] = f2h(lin_w[hh * APO + kk] * z);
        }
        memcpy(&bft[(size_t)cid * 8], tmp, 16);
    }
}

// ---------------------------------------------------------------------------
// Kernel 1: ap[b,h,i,j] + fused atoms_emb[l,b,d] (block (i,b) == (l,b)).
// One block (512 thr, 8 waves) per (b,i). Two k-phases of 64, 32 KB LDS slice
// per phase -> 4 blocks/CU at (512,8).
// Staging now uses global_load_lds width-16 with the XOR swizzle applied to
// the SOURCE chunk index (LDS dest linear): LDS position p holds src chunk
// p ^ (row&15) — identical content mapping to the previous reg-staged
// version, so the read side is unchanged. Kills all stage VGPRs + ds_writes.
// B-fragments loaded per-phase (8 live VGPRs instead of 16).
// Epilogue vectorized: int4 bonds/atoms loads, float4 store.
// ---------------------------------------------------------------------------
__global__ __launch_bounds__(512, 8) void ap_kernel(
    const int*            __restrict__ atoms,
    const int*            __restrict__ chirals,
    const float*          __restrict__ coords,
    const int*            __restrict__ bonds,
    const unsigned*       __restrict__ pack,
    const unsigned short* __restrict__ bft,
    const float*          __restrict__ atype_emb,
    const float*          __restrict__ chiral_emb,
    const float*          __restrict__ bond_emb,
    const float*          __restrict__ lin_b,
    float*                __restrict__ out1,   // atoms_emb [L,B,D]
    float*                __restrict__ out2)   // ap [B,NHEAD,L,L]
{
    const int i    = blockIdx.x;
    const int b    = blockIdx.y;
    const int t    = threadIdx.x;
    const int lane = t & 63;
    const int wave = t >> 6;
    const int h    = lane & 15;
    const int quad = lane >> 4;

    __shared__ unsigned tbl[ATOM_VOC * 64];   // 32 KB: one phase's slice

    const int ai = atoms[b * NL + i];
    const unsigned* src = pack + (size_t)ai * (ATOM_VOC * APO);

    // ---- phase-0 stage: async, source pre-swizzled, LDS linear ----
#pragma unroll
    for (int itx = 0; itx < 4; ++itx) {
        const int c   = itx * 512 + t;     // 16B-chunk id, 0..2047
        const int row = c >> 4;            // v
        const int cc  = c & 15;            // chunk within phase row
        gload_lds16(src + ((size_t)row * 32 + (cc ^ (row & 15))) * 4,
                    &tbl[(itx * 512 + wave * 64) * 4]);
    }

    // ---- fused atoms_emb: out1[i, b, t] (t == d, 512 threads) ----
    {
        const int ch = chirals[b * NL + i];
        out1[((size_t)i * NB + b) * D_MODEL + t] =
            atype_emb[(size_t)ai * D_MODEL + t] +
            chiral_emb[(size_t)ch * D_MODEL + t];
    }

    const float lbh = lin_b[h];
    const float cix = coords[((size_t)b * NL + i) * 3 + 0];
    const float ciy = coords[((size_t)b * NL + i) * 3 + 1];
    const float ciz = coords[((size_t)b * NL + i) * 3 + 2];

    // ---- per-iteration j metadata (3 iters) ----
    int     jv[3];
    __half2 jd2[3];
#pragma unroll
    for (int it = 0; it < 3; ++it) {
        const int j = it * 128 + wave * 16 + h;
        jv[it] = atoms[b * NL + j];
        const float dx = coords[((size_t)b * NL + j) * 3 + 0] - cix;
        const float dy = coords[((size_t)b * NL + j) * 3 + 1] - ciy;
        const float dz = coords[((size_t)b * NL + j) * 3 + 2] - ciz;
        jd2[it] = __half2half2(__float2half(
            sqrtf(fmaf(dx, dx, fmaf(dy, dy, dz * dz)) + 1e-12f)));
    }

    f32x4 acc[3] = {{0.f,0.f,0.f,0.f},{0.f,0.f,0.f,0.f},{0.f,0.f,0.f,0.f}};

#pragma unroll
    for (int ph = 0; ph < 2; ++ph) {
        if (ph) {
            __syncthreads();   // drain phase-0 readers before overwrite
#pragma unroll
            for (int itx = 0; itx < 4; ++itx) {
                const int c   = itx * 512 + t;
                const int row = c >> 4;
                const int cc  = c & 15;
                gload_lds16(src + ((size_t)row * 32 + 16 + (cc ^ (row & 15))) * 4,
                            &tbl[(itx * 512 + wave * 64) * 4]);
            }
        }
        // per-phase B fragments (bft is 4 KB, L1-hot; halves live-register cost)
        f16x8 bfA, bfB;
        memcpy(&bfA, bft + ((size_t)((ph * 2 + 0) * 4 + quad) * 16 + h) * 8, 16);
        memcpy(&bfB, bft + ((size_t)((ph * 2 + 1) * 4 + quad) * 16 + h) * 8, 16);
        __syncthreads();       // vmcnt(0) drain: stage landed

#pragma unroll
        for (int it = 0; it < 3; ++it) {
            const int v  = jv[it];
            const int vb = v * 64;
            const int vx = v & 15;
            const __half2 d2 = jd2[it];
#pragma unroll
            for (int ks2 = 0; ks2 < 2; ++ks2) {
                const u32x4 wch = *(const u32x4*)&tbl[vb + 4 * ((ks2 * 4 + quad) ^ vx)];
                const u32x4 bch = *(const u32x4*)&tbl[vb + 4 * ((8 + ks2 * 4 + quad) ^ vx)];
                unsigned afw[4];
#pragma unroll
                for (int q = 0; q < 4; ++q) {
                    __half2 w2, b2;
                    unsigned wd = wch[q], bd = bch[q];
                    memcpy(&w2, &wd, 4); memcpy(&b2, &bd, 4);
                    __half2 u2  = __hfma2(w2, d2, b2);
                    __half2 nm2 = __hmul2(u2, __hneg2(u2));   // -u^2
                    __half2 g2  = h2exp2(nm2);                // exp2(-u^2)
                    memcpy(&afw[q], &g2, 4);
                }
                f16x8 af;
                memcpy(&af, afw, 16);
                acc[it] = __builtin_amdgcn_mfma_f32_16x16x32_f16(
                    af, ks2 ? bfB : bfA, acc[it], 0, 0, 0);
            }
        }
    }

    // ---- epilogue: C row = quad*4+r, col = h; vectorized loads/stores ----
    const size_t bondrow = ((size_t)b * NL + i) * NL;
    float* op = out2 + (((size_t)(b * NHEAD + h)) * NL + i) * NL;
#pragma unroll
    for (int it = 0; it < 3; ++it) {
        const int jb = it * 128 + wave * 16 + quad * 4;
        const int4 bd = *(const int4*)(bonds + bondrow + jb);
        const int4 aj = *(const int4*)(atoms + b * NL + jb);
        float4 vv;
        vv.x = acc[it][0] + lbh + bond_emb[bd.x * NHEAD + h];
        vv.y = acc[it][1] + lbh + bond_emb[bd.y * NHEAD + h];
        vv.z = acc[it][2] + lbh + bond_emb[bd.z * NHEAD + h];
        vv.w = acc[it][3] + lbh + bond_emb[bd.w * NHEAD + h];
        if (aj.x == 0) vv.x = -1.0e30f;   // finite -inf sentinel
        if (aj.y == 0) vv.y = -1.0e30f;
        if (aj.z == 0) vv.z = -1.0e30f;
        if (aj.w == 0) vv.w = -1.0e30f;
        *(float4*)(op + jb) = vv;
    }
}

extern "C" void kernel_launch(void* const* d_in, const int* in_sizes, int n_in,
                              void* d_out, int out_size, void* d_ws, size_t ws_size,
                              hipStream_t stream)
{
    const int*   atoms      = (const int*)d_in[0];
    const int*   chirals    = (const int*)d_in[1];
    const float* coords     = (const float*)d_in[2];
    const int*   bonds      = (const int*)d_in[3];
    const float* atype_emb  = (const float*)d_in[4];
    const float* chiral_emb = (const float*)d_in[5];
    const float* apw        = (const float*)d_in[6];
    const float* apb        = (const float*)d_in[7];
    const float* means      = (const float*)d_in[8];
    const float* stds       = (const float*)d_in[9];
    const float* bond_emb   = (const float*)d_in[10];
    const float* lin_w      = (const float*)d_in[11];
    const float* lin_b      = (const float*)d_in[12];
    float* out = (float*)d_out;

    unsigned* pack = (unsigned*)d_ws;                      // 8 MB
    unsigned short* bftp = (unsigned short*)((char*)d_ws + (size_t)PACK_DWORDS * 4);

    // Kernel 0: repack tables (+ B-fragment table); ws re-poisoned each call
    pack_kernel<<<dim3((ATOM_VOC * ATOM_VOC) / 8), dim3(256), 0, stream>>>(
        apw, apb, means, stds, lin_w, pack, bftp, 1);

    // Kernel 1: atoms_emb (fused) at offset 0, ap at offset L*B*D
    {
        float* out2 = out + (size_t)NL * NB * D_MODEL;
        ap_kernel<<<dim3(NL, NB), dim3(512), 0, stream>>>(
            atoms, chirals, coords, bonds, pack, bftp,
            atype_emb, chiral_emb, bond_emb, lin_b, out, out2);
    }
}

// Round 2
// 128.676 us; speedup vs baseline: 1.0640x; 1.0242x over previous
//
#include <hip/hip_runtime.h>
#include <hip/hip_fp16.h>
#include <math.h>
#include <string.h>

#define ATOM_VOC 128
#define APO      128
#define NHEAD    16
#define D_MODEL  512
#define NB       4
#define NL       384

typedef __attribute__((ext_vector_type(8))) _Float16 f16x8;
typedef __attribute__((ext_vector_type(4))) float    f32x4;
typedef __attribute__((ext_vector_type(4))) unsigned u32x4;

#define PACK_DWORDS (ATOM_VOC * ATOM_VOC * APO)   // 2M dwords = 8 MB
#define BFT_SHORTS  (4 * 4 * 16 * 8)              // 2048 f16 = 4 KB

static __device__ inline unsigned short f2h(float x) {
    __half h = __float2half(x);
    unsigned short u; memcpy(&u, &h, 2); return u;
}

// async 16B global->LDS (wave-uniform LDS base + lane*16; source is per-lane)
static __device__ inline void gload_lds16(const void* g, void* l) {
    __builtin_amdgcn_global_load_lds(
        (const __attribute__((address_space(1))) void*)g,
        (__attribute__((address_space(3))) void*)l, 16, 0, 0);
}

// ---------------------------------------------------------------------------
// Kernel 0: packed fp16 table. Row (128 dwords = 512 B) per (ai, v), layout:
//   [phase0: 32 w-pair dw | 32 b-pair dw][phase1: 32 w-pair dw | 32 b-pair dw]
// pair p = (k=2p, k=2p+1); phase = p>>5.
//   w' = w*ag, b' = (b-mean)*ag, ag = sqrt(log2e)/(sqrt(2)*s).
// 2048 blocks x 256 thr; thread = (row r = t>>5, unit u = t&31),
// unit -> (ph, half, q): produces 4 dst dwords (u32x4) from 8 src floats.
// Block 0 additionally builds the f16 B-fragment table bft.
// ---------------------------------------------------------------------------
__global__ __launch_bounds__(256) void pack_kernel(
    const float* __restrict__ apw, const float* __restrict__ apb,
    const float* __restrict__ means, const float* __restrict__ stds,
    const float* __restrict__ lin_w,
    unsigned* __restrict__ pack, unsigned short* __restrict__ bft, int write_bft)
{
    const int t     = threadIdx.x;     // 0..255
    const int r     = t >> 5;          // row within block, 0..7
    const int u     = t & 31;          // work unit within row
    const int ph    = u >> 4;          // k-phase (k<64 / k>=64)
    const int half  = (u >> 3) & 1;    // 0 = w, 1 = b
    const int q     = u & 7;           // 4-dword group within half
    const int rowid = blockIdx.x * 8 + r;
    const int ai    = rowid >> 7;
    const int v     = rowid & 127;
    const int kb    = ph * 64 + q * 8; // first k of the 8 handled here

    const size_t srcrow = ((size_t)v * ATOM_VOC + ai) * APO;
    const float* sp = (half ? apb : apw) + srcrow + kb;
    const float4 f0  = *(const float4*)(sp);
    const float4 f1  = *(const float4*)(sp + 4);
    const float4 sd0 = *(const float4*)(stds + kb);
    const float4 sd1 = *(const float4*)(stds + kb + 4);

    float x[8]  = {f0.x, f0.y, f0.z, f0.w, f1.x, f1.y, f1.z, f1.w};
    float ss[8] = {sd0.x, sd0.y, sd0.z, sd0.w, sd1.x, sd1.y, sd1.z, sd1.w};
    if (half) {
        const float4 m0 = *(const float4*)(means + kb);
        const float4 m1 = *(const float4*)(means + kb + 4);
        const float mm[8] = {m0.x, m0.y, m0.z, m0.w, m1.x, m1.y, m1.z, m1.w};
#pragma unroll
        for (int j = 0; j < 8; ++j) x[j] = x[j] - mm[j];
    }
    unsigned dw[4];
#pragma unroll
    for (int j = 0; j < 4; ++j) {
        const float ag0 = 0.84932180028802f / (fabsf(ss[2 * j])     + 1e-5f);
        const float ag1 = 0.84932180028802f / (fabsf(ss[2 * j + 1]) + 1e-5f);
        dw[j] = ((unsigned)f2h(x[2 * j + 1] * ag1) << 16) | f2h(x[2 * j] * ag0);
    }
    const int dst = ph * 64 + half * 32 + q * 4;
    *(u32x4*)&pack[((size_t)ai * ATOM_VOC + v) * APO + dst] = *(const u32x4*)dw;

    if (write_bft && blockIdx.x == 0) {
        const int cid  = t;            // 0..255
        const int ks   = cid >> 6;
        const int quad = (cid >> 4) & 3;
        const int hh   = cid & 15;
        const int kb2  = ks * 32 + quad * 8;
        unsigned short tmp[8];
#pragma unroll
        for (int uu = 0; uu < 8; ++uu) {
            const int kk = kb2 + uu;
            float z = 0.3989422804014327f / (fabsf(stds[kk]) + 1e-5f);
            tmp[uu] = f2h(lin_w[hh * APO + kk] * z);
        }
        memcpy(&bft[(size_t)cid * 8], tmp, 16);
    }
}

// ---------------------------------------------------------------------------
// Kernel 1: ap[b,h,i,j] + fused atoms_emb[l,b,d] (block (i,b) == (l,b)).
// One block (512 thr, 8 waves) per (b,i).
// Changes vs previous round:
//   * __launch_bounds__(512, 4): 128-VGPR budget -> no scratch spills.
//     (2 blocks/CU; LDS 64 KB/block also gives 2 blocks/CU, so no
//     occupancy is lost relative to the VGPR-implied limit.)
//   * One-shot staging: BOTH 32 KB phase slices issued up front into a
//     64 KB double buffer (8 global_load_lds/thread in flight), single
//     __syncthreads, then the whole compute loop runs with no further
//     barriers — removes the serial mid-kernel re-stage.
// Staging uses global_load_lds width-16 with the XOR swizzle applied to the
// SOURCE chunk index (LDS dest linear); read side uses the same XOR.
// ---------------------------------------------------------------------------
__global__ __launch_bounds__(512, 4) void ap_kernel(
    const int*            __restrict__ atoms,
    const int*            __restrict__ chirals,
    const float*          __restrict__ coords,
    const int*            __restrict__ bonds,
    const unsigned*       __restrict__ pack,
    const unsigned short* __restrict__ bft,
    const float*          __restrict__ atype_emb,
    const float*          __restrict__ chiral_emb,
    const float*          __restrict__ bond_emb,
    const float*          __restrict__ lin_b,
    float*                __restrict__ out1,   // atoms_emb [L,B,D]
    float*                __restrict__ out2)   // ap [B,NHEAD,L,L]
{
    const int i    = blockIdx.x;
    const int b    = blockIdx.y;
    const int t    = threadIdx.x;
    const int lane = t & 63;
    const int wave = t >> 6;
    const int h    = lane & 15;
    const int quad = lane >> 4;

    __shared__ unsigned tbl[2][ATOM_VOC * 64];   // 64 KB: both phase slices

    const int ai = atoms[b * NL + i];
    const unsigned* src = pack + (size_t)ai * (ATOM_VOC * APO);

    // ---- one-shot stage of both phases: async, source pre-swizzled ----
#pragma unroll
    for (int ph = 0; ph < 2; ++ph) {
#pragma unroll
        for (int itx = 0; itx < 4; ++itx) {
            const int c   = itx * 512 + t;     // 16B-chunk id, 0..2047
            const int row = c >> 4;            // v
            const int cc  = c & 15;            // chunk within phase row
            gload_lds16(src + ((size_t)row * 32 + ph * 16 + (cc ^ (row & 15))) * 4,
                        &tbl[ph][(itx * 512 + wave * 64) * 4]);
        }
    }

    // ---- fused atoms_emb: out1[i, b, t] (t == d, 512 threads) ----
    {
        const int ch = chirals[b * NL + i];
        out1[((size_t)i * NB + b) * D_MODEL + t] =
            atype_emb[(size_t)ai * D_MODEL + t] +
            chiral_emb[(size_t)ch * D_MODEL + t];
    }

    // ---- B fragments (bft is 4 KB, L1-hot) ----
    f16x8 bfrag[4];
#pragma unroll
    for (int ks = 0; ks < 4; ++ks)
        memcpy(&bfrag[ks], bft + ((size_t)((ks * 4 + quad) * 16 + h)) * 8, 16);
    const float lbh = lin_b[h];

    const float cix = coords[((size_t)b * NL + i) * 3 + 0];
    const float ciy = coords[((size_t)b * NL + i) * 3 + 1];
    const float ciz = coords[((size_t)b * NL + i) * 3 + 2];

    // ---- per-iteration j metadata (3 iters) ----
    int     jv[3];
    __half2 jd2[3];
#pragma unroll
    for (int it = 0; it < 3; ++it) {
        const int j = it * 128 + wave * 16 + h;
        jv[it] = atoms[b * NL + j];
        const float dx = coords[((size_t)b * NL + j) * 3 + 0] - cix;
        const float dy = coords[((size_t)b * NL + j) * 3 + 1] - ciy;
        const float dz = coords[((size_t)b * NL + j) * 3 + 2] - ciz;
        jd2[it] = __half2half2(__float2half(
            sqrtf(fmaf(dx, dx, fmaf(dy, dy, dz * dz)) + 1e-12f)));
    }

    f32x4 acc[3] = {{0.f,0.f,0.f,0.f},{0.f,0.f,0.f,0.f},{0.f,0.f,0.f,0.f}};

    __syncthreads();   // single drain: both phase slices landed

#pragma unroll
    for (int ph = 0; ph < 2; ++ph) {
#pragma unroll
        for (int it = 0; it < 3; ++it) {
            const int v  = jv[it];
            const int vb = v * 64;
            const int vx = v & 15;
            const __half2 d2 = jd2[it];
#pragma unroll
            for (int ks2 = 0; ks2 < 2; ++ks2) {
                const u32x4 wch = *(const u32x4*)&tbl[ph][vb + 4 * ((ks2 * 4 + quad) ^ vx)];
                const u32x4 bch = *(const u32x4*)&tbl[ph][vb + 4 * ((8 + ks2 * 4 + quad) ^ vx)];
                unsigned afw[4];
#pragma unroll
                for (int q = 0; q < 4; ++q) {
                    __half2 w2, b2;
                    unsigned wd = wch[q], bd = bch[q];
                    memcpy(&w2, &wd, 4); memcpy(&b2, &bd, 4);
                    __half2 u2  = __hfma2(w2, d2, b2);
                    __half2 nm2 = __hmul2(u2, __hneg2(u2));   // -u^2
                    __half2 g2  = h2exp2(nm2);                // exp2(-u^2)
                    memcpy(&afw[q], &g2, 4);
                }
                f16x8 af;
                memcpy(&af, afw, 16);
                acc[it] = __builtin_amdgcn_mfma_f32_16x16x32_f16(
                    af, bfrag[ph * 2 + ks2], acc[it], 0, 0, 0);
            }
        }
    }

    // ---- epilogue: C row = quad*4+r, col = h; vectorized loads/stores ----
    const size_t bondrow = ((size_t)b * NL + i) * NL;
    float* op = out2 + (((size_t)(b * NHEAD + h)) * NL + i) * NL;
#pragma unroll
    for (int it = 0; it < 3; ++it) {
        const int jb = it * 128 + wave * 16 + quad * 4;
        const int4 bd = *(const int4*)(bonds + bondrow + jb);
        const int4 aj = *(const int4*)(atoms + b * NL + jb);
        float4 vv;
        vv.x = acc[it][0] + lbh + bond_emb[bd.x * NHEAD + h];
        vv.y = acc[it][1] + lbh + bond_emb[bd.y * NHEAD + h];
        vv.z = acc[it][2] + lbh + bond_emb[bd.z * NHEAD + h];
        vv.w = acc[it][3] + lbh + bond_emb[bd.w * NHEAD + h];
        if (aj.x == 0) vv.x = -1.0e30f;   // finite -inf sentinel
        if (aj.y == 0) vv.y = -1.0e30f;
        if (aj.z == 0) vv.z = -1.0e30f;
        if (aj.w == 0) vv.w = -1.0e30f;
        *(float4*)(op + jb) = vv;
    }
}

extern "C" void kernel_launch(void* const* d_in, const int* in_sizes, int n_in,
                              void* d_out, int out_size, void* d_ws, size_t ws_size,
                              hipStream_t stream)
{
    const int*   atoms      = (const int*)d_in[0];
    const int*   chirals    = (const int*)d_in[1];
    const float* coords     = (const float*)d_in[2];
    const int*   bonds      = (const int*)d_in[3];
    const float* atype_emb  = (const float*)d_in[4];
    const float* chiral_emb = (const float*)d_in[5];
    const float* apw        = (const float*)d_in[6];
    const float* apb        = (const float*)d_in[7];
    const float* means      = (const float*)d_in[8];
    const float* stds       = (const float*)d_in[9];
    const float* bond_emb   = (const float*)d_in[10];
    const float* lin_w      = (const float*)d_in[11];
    const float* lin_b      = (const float*)d_in[12];
    float* out = (float*)d_out;

    unsigned* pack = (unsigned*)d_ws;                      // 8 MB
    unsigned short* bftp = (unsigned short*)((char*)d_ws + (size_t)PACK_DWORDS * 4);

    // Kernel 0: repack tables (+ B-fragment table); ws re-poisoned each call
    pack_kernel<<<dim3((ATOM_VOC * ATOM_VOC) / 8), dim3(256), 0, stream>>>(
        apw, apb, means, stds, lin_w, pack, bftp, 1);

    // Kernel 1: atoms_emb (fused) at offset 0, ap at offset L*B*D
    {
        float* out2 = out + (size_t)NL * NB * D_MODEL;
        ap_kernel<<<dim3(NL, NB), dim3(512), 0, stream>>>(
            atoms, chirals, coords, bonds, pack, bftp,
            atype_emb, chiral_emb, bond_emb, lin_b, out, out2);
    }
}

// Round 3
// 127.590 us; speedup vs baseline: 1.0731x; 1.0085x over previous
//
#include <hip/hip_runtime.h>
#include <hip/hip_fp16.h>
#include <math.h>
#include <string.h>

#define ATOM_VOC 128
#define APO      128
#define NHEAD    16
#define D_MODEL  512
#define NB       4
#define NL       384

typedef __attribute__((ext_vector_type(8))) _Float16 f16x8;
typedef __attribute__((ext_vector_type(4))) float    f32x4;
typedef __attribute__((ext_vector_type(4))) unsigned u32x4;

#define PACK_DWORDS (ATOM_VOC * ATOM_VOC * APO)   // 2M dwords = 8 MB
#define BFT_SHORTS  (4 * 4 * 16 * 8)              // 2048 f16 = 4 KB

static __device__ inline unsigned short f2h(float x) {
    __half h = __float2half(x);
    unsigned short u; memcpy(&u, &h, 2); return u;
}

// async 16B global->LDS (wave-uniform LDS base + lane*16; source is per-lane)
static __device__ inline void gload_lds16(const void* g, void* l) {
    __builtin_amdgcn_global_load_lds(
        (const __attribute__((address_space(1))) void*)g,
        (__attribute__((address_space(3))) void*)l, 16, 0, 0);
}

// ---------------------------------------------------------------------------
// Kernel 0: packed fp16 table. Row (128 dwords = 512 B) per (ai, v), layout:
//   [phase0: 32 w-pair dw | 32 b-pair dw][phase1: 32 w-pair dw | 32 b-pair dw]
// pair p = (k=2p, k=2p+1); phase = p>>5.
//   w' = w*ag, b' = (b-mean)*ag, ag = sqrt(log2e)/(sqrt(2)*s).
// 2048 blocks x 256 thr. Block 0 additionally builds the f16 B-fragment
// table bft. (Unchanged from round 2.)
// ---------------------------------------------------------------------------
__global__ __launch_bounds__(256) void pack_kernel(
    const float* __restrict__ apw, const float* __restrict__ apb,
    const float* __restrict__ means, const float* __restrict__ stds,
    const float* __restrict__ lin_w,
    unsigned* __restrict__ pack, unsigned short* __restrict__ bft, int write_bft)
{
    const int t     = threadIdx.x;     // 0..255
    const int r     = t >> 5;          // row within block, 0..7
    const int u     = t & 31;          // work unit within row
    const int ph    = u >> 4;          // k-phase (k<64 / k>=64)
    const int half  = (u >> 3) & 1;    // 0 = w, 1 = b
    const int q     = u & 7;           // 4-dword group within half
    const int rowid = blockIdx.x * 8 + r;
    const int ai    = rowid >> 7;
    const int v     = rowid & 127;
    const int kb    = ph * 64 + q * 8; // first k of the 8 handled here

    const size_t srcrow = ((size_t)v * ATOM_VOC + ai) * APO;
    const float* sp = (half ? apb : apw) + srcrow + kb;
    const float4 f0  = *(const float4*)(sp);
    const float4 f1  = *(const float4*)(sp + 4);
    const float4 sd0 = *(const float4*)(stds + kb);
    const float4 sd1 = *(const float4*)(stds + kb + 4);

    float x[8]  = {f0.x, f0.y, f0.z, f0.w, f1.x, f1.y, f1.z, f1.w};
    float ss[8] = {sd0.x, sd0.y, sd0.z, sd0.w, sd1.x, sd1.y, sd1.z, sd1.w};
    if (half) {
        const float4 m0 = *(const float4*)(means + kb);
        const float4 m1 = *(const float4*)(means + kb + 4);
        const float mm[8] = {m0.x, m0.y, m0.z, m0.w, m1.x, m1.y, m1.z, m1.w};
#pragma unroll
        for (int j = 0; j < 8; ++j) x[j] = x[j] - mm[j];
    }
    unsigned dw[4];
#pragma unroll
    for (int j = 0; j < 4; ++j) {
        const float ag0 = 0.84932180028802f / (fabsf(ss[2 * j])     + 1e-5f);
        const float ag1 = 0.84932180028802f / (fabsf(ss[2 * j + 1]) + 1e-5f);
        dw[j] = ((unsigned)f2h(x[2 * j + 1] * ag1) << 16) | f2h(x[2 * j] * ag0);
    }
    const int dst = ph * 64 + half * 32 + q * 4;
    *(u32x4*)&pack[((size_t)ai * ATOM_VOC + v) * APO + dst] = *(const u32x4*)dw;

    if (write_bft && blockIdx.x == 0) {
        const int cid  = t;            // 0..255
        const int ks   = cid >> 6;
        const int quad = (cid >> 4) & 3;
        const int hh   = cid & 15;
        const int kb2  = ks * 32 + quad * 8;
        unsigned short tmp[8];
#pragma unroll
        for (int uu = 0; uu < 8; ++uu) {
            const int kk = kb2 + uu;
            float z = 0.3989422804014327f / (fabsf(stds[kk]) + 1e-5f);
            tmp[uu] = f2h(lin_w[hh * APO + kk] * z);
        }
        memcpy(&bft[(size_t)cid * 8], tmp, 16);
    }
}

// ---------------------------------------------------------------------------
// Kernel 1: ap[b,h,i,j] + fused atoms_emb[l,b,d]. One block (512 thr) per
// (b,i). Changes vs round 2:
//   * Split-phase counted-vmcnt staging: issue ph0 loads first, metadata /
//     atoms_emb / epilogue-prefetch in the middle, ph1 loads LAST; then
//     s_waitcnt vmcnt(4) (only ph1's 4 loads may remain) + raw s_barrier
//     -> ph0 compute overlaps ph1's in-flight 32 KB. vmcnt(0)+barrier
//     before ph1 compute. Every waitcnt/barrier is bracketed with
//     sched_barrier(0) (rule #18: raw s_barrier is not a compiler fence).
//   * bonds/atoms epilogue int4 loads prefetched before the first barrier
//     (retire under the stage wait; epilogue tail is gather+store only).
// ---------------------------------------------------------------------------
__global__ __launch_bounds__(512, 4) void ap_kernel(
    const int*            __restrict__ atoms,
    const int*            __restrict__ chirals,
    const float*          __restrict__ coords,
    const int*            __restrict__ bonds,
    const unsigned*       __restrict__ pack,
    const unsigned short* __restrict__ bft,
    const float*          __restrict__ atype_emb,
    const float*          __restrict__ chiral_emb,
    const float*          __restrict__ bond_emb,
    const float*          __restrict__ lin_b,
    float*                __restrict__ out1,   // atoms_emb [L,B,D]
    float*                __restrict__ out2)   // ap [B,NHEAD,L,L]
{
    const int i    = blockIdx.x;
    const int b    = blockIdx.y;
    const int t    = threadIdx.x;
    const int lane = t & 63;
    const int wave = t >> 6;
    const int h    = lane & 15;
    const int quad = lane >> 4;

    __shared__ unsigned tbl[2][ATOM_VOC * 64];   // 64 KB: both phase slices

    const int ai = atoms[b * NL + i];
    const unsigned* src = pack + (size_t)ai * (ATOM_VOC * APO);

    // ---- issue ph0 stage (oldest VMEM after the ai load) ----
#pragma unroll
    for (int itx = 0; itx < 4; ++itx) {
        const int c   = itx * 512 + t;     // 16B-chunk id, 0..2047
        const int row = c >> 4;            // v
        const int cc  = c & 15;            // chunk within phase row
        gload_lds16(src + ((size_t)row * 32 + (cc ^ (row & 15))) * 4,
                    &tbl[0][(itx * 512 + wave * 64) * 4]);
    }
    __builtin_amdgcn_sched_barrier(0);

    // ---- fused atoms_emb: out1[i, b, t] (t == d, 512 threads) ----
    {
        const int ch = chirals[b * NL + i];
        out1[((size_t)i * NB + b) * D_MODEL + t] =
            atype_emb[(size_t)ai * D_MODEL + t] +
            chiral_emb[(size_t)ch * D_MODEL + t];
    }

    // ---- B fragments (bft is 4 KB, L1/L2-hot) ----
    f16x8 bfrag[4];
#pragma unroll
    for (int ks = 0; ks < 4; ++ks)
        memcpy(&bfrag[ks], bft + ((size_t)((ks * 4 + quad) * 16 + h)) * 8, 16);
    const float lbh = lin_b[h];

    const float cix = coords[((size_t)b * NL + i) * 3 + 0];
    const float ciy = coords[((size_t)b * NL + i) * 3 + 1];
    const float ciz = coords[((size_t)b * NL + i) * 3 + 2];

    // ---- per-iteration j metadata (3 iters) ----
    int     jv[3];
    __half2 jd2[3];
#pragma unroll
    for (int it = 0; it < 3; ++it) {
        const int j = it * 128 + wave * 16 + h;
        jv[it] = atoms[b * NL + j];
        const float dx = coords[((size_t)b * NL + j) * 3 + 0] - cix;
        const float dy = coords[((size_t)b * NL + j) * 3 + 1] - ciy;
        const float dz = coords[((size_t)b * NL + j) * 3 + 2] - ciz;
        jd2[it] = __half2half2(__float2half(
            sqrtf(fmaf(dx, dx, fmaf(dy, dy, dz * dz)) + 1e-12f)));
    }

    // ---- epilogue prefetch: bonds + key-atom int4 (retire under stage) ----
    const size_t bondrow = ((size_t)b * NL + i) * NL;
    int4 bd4[3], aj4[3];
#pragma unroll
    for (int it = 0; it < 3; ++it) {
        const int jb = it * 128 + wave * 16 + quad * 4;
        bd4[it] = *(const int4*)(bonds + bondrow + jb);
        aj4[it] = *(const int4*)(atoms + b * NL + jb);
    }

    f32x4 acc[3] = {{0.f,0.f,0.f,0.f},{0.f,0.f,0.f,0.f},{0.f,0.f,0.f,0.f}};

    // ---- issue ph1 stage LAST (youngest 4 VMEM ops per thread) ----
    __builtin_amdgcn_sched_barrier(0);
#pragma unroll
    for (int itx = 0; itx < 4; ++itx) {
        const int c   = itx * 512 + t;
        const int row = c >> 4;
        const int cc  = c & 15;
        gload_lds16(src + ((size_t)row * 32 + 16 + (cc ^ (row & 15))) * 4,
                    &tbl[1][(itx * 512 + wave * 64) * 4]);
    }
    __builtin_amdgcn_sched_barrier(0);

    // ---- wait: everything older than ph1 (i.e. ph0 + meta) retired ----
    asm volatile("s_waitcnt vmcnt(4)" ::: "memory");
    __builtin_amdgcn_s_barrier();
    __builtin_amdgcn_sched_barrier(0);

#pragma unroll
    for (int ph = 0; ph < 2; ++ph) {
        if (ph) {
            __builtin_amdgcn_sched_barrier(0);
            asm volatile("s_waitcnt vmcnt(0)" ::: "memory");
            __builtin_amdgcn_s_barrier();
            __builtin_amdgcn_sched_barrier(0);
        }
#pragma unroll
        for (int it = 0; it < 3; ++it) {
            const int v  = jv[it];
            const int vb = v * 64;
            const int vx = v & 15;
            const __half2 d2 = jd2[it];
#pragma unroll
            for (int ks2 = 0; ks2 < 2; ++ks2) {
                const u32x4 wch = *(const u32x4*)&tbl[ph][vb + 4 * ((ks2 * 4 + quad) ^ vx)];
                const u32x4 bch = *(const u32x4*)&tbl[ph][vb + 4 * ((8 + ks2 * 4 + quad) ^ vx)];
                unsigned afw[4];
#pragma unroll
                for (int q = 0; q < 4; ++q) {
                    __half2 w2, b2;
                    unsigned wd = wch[q], bd = bch[q];
                    memcpy(&w2, &wd, 4); memcpy(&b2, &bd, 4);
                    __half2 u2  = __hfma2(w2, d2, b2);
                    __half2 nm2 = __hmul2(u2, __hneg2(u2));   // -u^2
                    __half2 g2  = h2exp2(nm2);                // exp2(-u^2)
                    memcpy(&afw[q], &g2, 4);
                }
                f16x8 af;
                memcpy(&af, afw, 16);
                acc[it] = __builtin_amdgcn_mfma_f32_16x16x32_f16(
                    af, bfrag[ph * 2 + ks2], acc[it], 0, 0, 0);
            }
        }
    }

    // ---- epilogue: C row = quad*4+r, col = h; bd/aj already in regs ----
    float* op = out2 + (((size_t)(b * NHEAD + h)) * NL + i) * NL;
#pragma unroll
    for (int it = 0; it < 3; ++it) {
        const int jb = it * 128 + wave * 16 + quad * 4;
        float4 vv;
        vv.x = acc[it][0] + lbh + bond_emb[bd4[it].x * NHEAD + h];
        vv.y = acc[it][1] + lbh + bond_emb[bd4[it].y * NHEAD + h];
        vv.z = acc[it][2] + lbh + bond_emb[bd4[it].z * NHEAD + h];
        vv.w = acc[it][3] + lbh + bond_emb[bd4[it].w * NHEAD + h];
        if (aj4[it].x == 0) vv.x = -1.0e30f;   // finite -inf sentinel
        if (aj4[it].y == 0) vv.y = -1.0e30f;
        if (aj4[it].z == 0) vv.z = -1.0e30f;
        if (aj4[it].w == 0) vv.w = -1.0e30f;
        *(float4*)(op + jb) = vv;
    }
}

extern "C" void kernel_launch(void* const* d_in, const int* in_sizes, int n_in,
                              void* d_out, int out_size, void* d_ws, size_t ws_size,
                              hipStream_t stream)
{
    const int*   atoms      = (const int*)d_in[0];
    const int*   chirals    = (const int*)d_in[1];
    const float* coords     = (const float*)d_in[2];
    const int*   bonds      = (const int*)d_in[3];
    const float* atype_emb  = (const float*)d_in[4];
    const float* chiral_emb = (const float*)d_in[5];
    const float* apw        = (const float*)d_in[6];
    const float* apb        = (const float*)d_in[7];
    const float* means      = (const float*)d_in[8];
    const float* stds       = (const float*)d_in[9];
    const float* bond_emb   = (const float*)d_in[10];
    const float* lin_w      = (const float*)d_in[11];
    const float* lin_b      = (const float*)d_in[12];
    float* out = (float*)d_out;

    unsigned* pack = (unsigned*)d_ws;                      // 8 MB
    unsigned short* bftp = (unsigned short*)((char*)d_ws + (size_t)PACK_DWORDS * 4);

    // Kernel 0: repack tables (+ B-fragment table); ws re-poisoned each call
    pack_kernel<<<dim3((ATOM_VOC * ATOM_VOC) / 8), dim3(256), 0, stream>>>(
        apw, apb, means, stds, lin_w, pack, bftp, 1);

    // Kernel 1: atoms_emb (fused) at offset 0, ap at offset L*B*D
    {
        float* out2 = out + (size_t)NL * NB * D_MODEL;
        ap_kernel<<<dim3(NL, NB), dim3(512), 0, stream>>>(
            atoms, chirals, coords, bonds, pack, bftp,
            atype_emb, chiral_emb, bond_emb, lin_b, out, out2);
    }
}